// Round 1
// baseline (1645.333 us; speedup 1.0000x reference)
//
#include <hip/hip_runtime.h>
#include <hip/hip_bf16.h>
#include <stdint.h>

typedef __bf16 bf16_t;
typedef __bf16 bf16x8 __attribute__((ext_vector_type(8)));
typedef __bf16 bf16x4 __attribute__((ext_vector_type(4)));
typedef float f32x4 __attribute__((ext_vector_type(4)));

typedef __attribute__((address_space(1))) unsigned gu32;
typedef __attribute__((address_space(3))) unsigned lu32;

__device__ __forceinline__ unsigned short f2bf(float f) {
  unsigned u = __builtin_bit_cast(unsigned, f);
  unsigned r = (u + 0x7FFFu + ((u >> 16) & 1u)) >> 16;
  return (unsigned short)r;
}

__device__ __forceinline__ void gload_lds16(const bf16_t* g, bf16_t* l) {
  __builtin_amdgcn_global_load_lds((const gu32*)(const void*)g, (lu32*)(void*)l, 16, 0, 0);
}

// ---------------- fp32 -> bf16 convert (vectorized) ----------------
__global__ __launch_bounds__(256) void k_cvt_bf16(const float* __restrict__ in,
                                                  bf16_t* __restrict__ out, int n4) {
  int i = blockIdx.x * 256 + threadIdx.x;
  if (i >= n4) return;
  float4 v = ((const float4*)in)[i];
  ushort4 o;
  o.x = f2bf(v.x); o.y = f2bf(v.y); o.z = f2bf(v.z); o.w = f2bf(v.w);
  ((ushort4*)out)[i] = o;
}

// ---------------- fp32 RxC -> bf16 CxR transpose ----------------
__global__ __launch_bounds__(256) void k_transpose_cvt(const float* __restrict__ in,
                                                       bf16_t* __restrict__ out, int R, int C) {
  __shared__ float t[32][33];
  int c0 = blockIdx.x * 32, r0 = blockIdx.y * 32;
  int tx = threadIdx.x & 31, ty = threadIdx.x >> 5;
  #pragma unroll
  for (int r = 0; r < 4; ++r) {
    int rr = ty + r * 8;
    t[rr][tx] = in[(size_t)(r0 + rr) * C + c0 + tx];
  }
  __syncthreads();
  #pragma unroll
  for (int r = 0; r < 4; ++r) {
    int rr = ty + r * 8;
    ((unsigned short*)out)[(size_t)(c0 + rr) * R + r0 + tx] = f2bf(t[tx][rr]);
  }
}

// ---------------- bf16 batched RxC -> CxR transpose (for V) ----------------
__global__ __launch_bounds__(256) void k_transpose_bf16(const bf16_t* __restrict__ in,
                                                        bf16_t* __restrict__ out, int R, int C) {
  __shared__ unsigned short t[32][33];
  const unsigned short* ip = (const unsigned short*)in + (size_t)blockIdx.z * R * C;
  unsigned short* op = (unsigned short*)out + (size_t)blockIdx.z * R * C;
  int c0 = blockIdx.x * 32, r0 = blockIdx.y * 32;
  int tx = threadIdx.x & 31, ty = threadIdx.x >> 5;
  #pragma unroll
  for (int r = 0; r < 4; ++r) {
    int rr = ty + r * 8;
    t[rr][tx] = ip[(size_t)(r0 + rr) * C + c0 + tx];
  }
  __syncthreads();
  #pragma unroll
  for (int r = 0; r < 4; ++r) {
    int rr = ty + r * 8;
    op[(size_t)(c0 + rr) * R + r0 + tx] = t[tx][rr];
  }
}

// ---------------- QKV GEMM: xb[4096][4096] @ wT[6144][4096]^T ----------------
// m97 structure: 128x128 tile, BK=32, 4 waves (each 64x64 = 4x4 16x16 frags)
#define BK 32
__global__ __launch_bounds__(256) void k_gemm_qkv(
    const bf16_t* __restrict__ A, const bf16_t* __restrict__ Bm,
    const float* __restrict__ qb, const float* __restrict__ kb, const float* __restrict__ vb,
    const float* __restrict__ cosT, const float* __restrict__ sinT,
    const int* __restrict__ start_pos,
    bf16_t* __restrict__ Qr, bf16_t* __restrict__ Kr, bf16_t* __restrict__ Vr) {
  __shared__ __attribute__((aligned(16))) bf16_t sA[128 * BK];
  __shared__ __attribute__((aligned(16))) bf16_t sB[128 * BK];
  const int tid = threadIdx.x;
  const int lane = tid & 63;
  const int wv = tid >> 6;
  const int wr = wv >> 1, wc = wv & 1;
  const int brow = blockIdx.x * 128;
  const int bcol = blockIdx.y * 128;
  const int K = 4096;
  const int l4 = lane >> 2;       // 0..15
  const int c8 = (lane & 3) * 8;  // 0,8,16,24
  const int fr = lane & 15;
  const int fq = lane >> 4;

  f32x4 acc[4][4];
  #pragma unroll
  for (int i = 0; i < 4; ++i)
    #pragma unroll
    for (int j = 0; j < 4; ++j) acc[i][j] = (f32x4){0.f, 0.f, 0.f, 0.f};

  for (int k0 = 0; k0 < K; k0 += BK) {
    #pragma unroll
    for (int r = 0; r < 2; ++r) {
      int chunk = r * 4 + wv;
      int row = chunk * 16 + l4;
      gload_lds16(A + (size_t)(brow + row) * K + k0 + c8, sA + chunk * 512);
      gload_lds16(Bm + (size_t)(bcol + row) * K + k0 + c8, sB + chunk * 512);
    }
    __syncthreads();
    bf16x8 af[4], bfv[4];
    #pragma unroll
    for (int mi = 0; mi < 4; ++mi)
      af[mi] = *(const bf16x8*)(sA + (wr * 64 + mi * 16 + fr) * BK + fq * 8);
    #pragma unroll
    for (int ni = 0; ni < 4; ++ni)
      bfv[ni] = *(const bf16x8*)(sB + (wc * 64 + ni * 16 + fr) * BK + fq * 8);
    #pragma unroll
    for (int mi = 0; mi < 4; ++mi)
      #pragma unroll
      for (int ni = 0; ni < 4; ++ni)
        acc[mi][ni] = __builtin_amdgcn_mfma_f32_16x16x32_bf16(af[mi], bfv[ni], acc[mi][ni], 0, 0, 0);
    __syncthreads();
  }

  // epilogue: bias + RoPE + scatter to per-head layouts
  const int sp = *start_pos;
  #pragma unroll
  for (int mi = 0; mi < 4; ++mi) {
    #pragma unroll
    for (int ni = 0; ni < 4; ++ni) {
      int col = bcol + wc * 64 + ni * 16 + fr;
      float bias = (col < 4096) ? qb[col] : (col < 5120 ? kb[col - 4096] : vb[col - 5120]);
      #pragma unroll
      for (int j = 0; j < 4; ++j) {
        int row = brow + wr * 64 + mi * 16 + fq * 4 + j;
        int b = row >> 11, s = row & 2047;
        int d = col & 127;
        float v = acc[mi][ni][j] + bias;
        float partner = __shfl_xor(v, 1);
        if (col < 5120) {  // RoPE on q,k
          int dd = d >> 1;
          float cc = cosT[(size_t)(sp + s) * 64 + dd];
          float sn = sinT[(size_t)(sp + s) * 64 + dd];
          v = (d & 1) ? (partner * sn + v * cc) : (v * cc - partner * sn);
        }
        unsigned short bvv = f2bf(v);
        if (col < 4096) {
          int h = col >> 7;
          ((unsigned short*)Qr)[(((size_t)b * 32 + h) * 2048 + s) * 128 + d] = bvv;
        } else if (col < 5120) {
          int hk = (col - 4096) >> 7;
          ((unsigned short*)Kr)[(((size_t)b * 8 + hk) * 2048 + s) * 128 + d] = bvv;
        } else {
          int hk = (col - 5120) >> 7;
          ((unsigned short*)Vr)[(((size_t)b * 8 + hk) * 2048 + s) * 128 + d] = bvv;
        }
      }
    }
  }
}

// ---------------- flash attention: GQA, causal ----------------
// block = 4 waves; wave owns 16 q rows; KV tiles of 32; swapped QK^T.
__global__ __launch_bounds__(256) void k_attn(
    const bf16_t* __restrict__ Qr, const bf16_t* __restrict__ Kr,
    const bf16_t* __restrict__ Vt, bf16_t* __restrict__ Ob) {
  __shared__ __attribute__((aligned(16))) bf16_t p_lds[4][16][32];
  const int lane = threadIdx.x & 63;
  const int w = threadIdx.x >> 6;
  const int b = blockIdx.y >> 5, h = blockIdx.y & 31;
  const int hk = h >> 2;
  const bf16_t* Qb = Qr + (((size_t)b * 32 + h) * 2048) * 128;
  const bf16_t* Kb = Kr + (((size_t)b * 8 + hk) * 2048) * 128;
  const bf16_t* Vb = Vt + (((size_t)b * 8 + hk) * 128) * 2048;
  const int q0 = blockIdx.x * 64 + w * 16;
  const int fr = lane & 15, fq = lane >> 4;

  bf16x8 qf[4];
  #pragma unroll
  for (int c = 0; c < 4; ++c)
    qf[c] = *(const bf16x8*)(Qb + (size_t)(q0 + fr) * 128 + c * 32 + fq * 8);

  f32x4 o[8];
  #pragma unroll
  for (int i = 0; i < 8; ++i) o[i] = (f32x4){0.f, 0.f, 0.f, 0.f};
  float m_q = -1e30f, l_q = 0.f;
  const float sc = 0.08838834764831845f;  // 1/sqrt(128)
  const int qglob = q0 + fr;
  const int ntiles = (q0 + 15) / 32 + 1;

  for (int t = 0; t < ntiles; ++t) {
    const int kv0 = t * 32;
    f32x4 st0 = {0.f, 0.f, 0.f, 0.f}, st1 = {0.f, 0.f, 0.f, 0.f};
    #pragma unroll
    for (int c = 0; c < 4; ++c) {
      bf16x8 kf0 = *(const bf16x8*)(Kb + (size_t)(kv0 + fr) * 128 + c * 32 + fq * 8);
      bf16x8 kf1 = *(const bf16x8*)(Kb + (size_t)(kv0 + 16 + fr) * 128 + c * 32 + fq * 8);
      st0 = __builtin_amdgcn_mfma_f32_16x16x32_bf16(kf0, qf[c], st0, 0, 0, 0);
      st1 = __builtin_amdgcn_mfma_f32_16x16x32_bf16(kf1, qf[c], st1, 0, 0, 0);
    }
    // scale + causal mask; S^T layout: row(kv)=fq*4+j, col(q)=fr
    float pm = -1e30f;
    float p0[4], p1[4];
    #pragma unroll
    for (int j = 0; j < 4; ++j) {
      int kvr = kv0 + fq * 4 + j;
      float s0 = (kvr <= qglob) ? st0[j] * sc : -1e30f;
      float s1 = (kvr + 16 <= qglob) ? st1[j] * sc : -1e30f;
      p0[j] = s0; p1[j] = s1;
      pm = fmaxf(pm, fmaxf(s0, s1));
    }
    pm = fmaxf(pm, __shfl_xor(pm, 16));
    pm = fmaxf(pm, __shfl_xor(pm, 32));
    float m_new = fmaxf(m_q, pm);
    float scale_f = __expf(m_q - m_new);
    float ps = 0.f;
    #pragma unroll
    for (int j = 0; j < 4; ++j) {
      p0[j] = __expf(p0[j] - m_new);
      p1[j] = __expf(p1[j] - m_new);
      ps += p0[j] + p1[j];
    }
    ps += __shfl_xor(ps, 16);
    ps += __shfl_xor(ps, 32);
    l_q = l_q * scale_f + ps;
    m_q = m_new;
    // P^T -> LDS as [q][kv] bf16
    bf16x4 pk0, pk1;
    #pragma unroll
    for (int j = 0; j < 4; ++j) { pk0[j] = (bf16_t)p0[j]; pk1[j] = (bf16_t)p1[j]; }
    *(bf16x4*)&p_lds[w][fr][fq * 4] = pk0;
    *(bf16x4*)&p_lds[w][fr][16 + fq * 4] = pk1;
    // rescale O (rows are q = fq*4+j; stats live in lanes 0..15)
    #pragma unroll
    for (int j = 0; j < 4; ++j) {
      float sj = __shfl(scale_f, fq * 4 + j);
      #pragma unroll
      for (int df = 0; df < 8; ++df) o[df][j] *= sj;
    }
    asm volatile("s_waitcnt lgkmcnt(0)" ::: "memory");
    bf16x8 pa = *(const bf16x8*)&p_lds[w][fr][fq * 8];
    #pragma unroll
    for (int df = 0; df < 8; ++df) {
      bf16x8 vf = *(const bf16x8*)(Vb + (size_t)(df * 16 + fr) * 2048 + kv0 + fq * 8);
      o[df] = __builtin_amdgcn_mfma_f32_16x16x32_bf16(pa, vf, o[df], 0, 0, 0);
    }
  }
  // normalize + write O[b][s][h*128+d]
  #pragma unroll
  for (int j = 0; j < 4; ++j) {
    float lj = __shfl(l_q, fq * 4 + j);
    float rl = 1.f / lj;
    int srow = q0 + fq * 4 + j;
    #pragma unroll
    for (int df = 0; df < 8; ++df) {
      int dcol = df * 16 + fr;
      ((unsigned short*)Ob)[((size_t)b * 2048 + srow) * 4096 + h * 128 + dcol] =
          f2bf(o[df][j] * rl);
    }
  }
}

// ---------------- out projection GEMM: Ob @ owT^T -> f32 out ----------------
__global__ __launch_bounds__(256) void k_gemm_out(
    const bf16_t* __restrict__ A, const bf16_t* __restrict__ Bm, float* __restrict__ out) {
  __shared__ __attribute__((aligned(16))) bf16_t sA[128 * BK];
  __shared__ __attribute__((aligned(16))) bf16_t sB[128 * BK];
  const int tid = threadIdx.x;
  const int lane = tid & 63;
  const int wv = tid >> 6;
  const int wr = wv >> 1, wc = wv & 1;
  const int brow = blockIdx.x * 128;
  const int bcol = blockIdx.y * 128;
  const int K = 4096;
  const int l4 = lane >> 2;
  const int c8 = (lane & 3) * 8;
  const int fr = lane & 15;
  const int fq = lane >> 4;

  f32x4 acc[4][4];
  #pragma unroll
  for (int i = 0; i < 4; ++i)
    #pragma unroll
    for (int j = 0; j < 4; ++j) acc[i][j] = (f32x4){0.f, 0.f, 0.f, 0.f};

  for (int k0 = 0; k0 < K; k0 += BK) {
    #pragma unroll
    for (int r = 0; r < 2; ++r) {
      int chunk = r * 4 + wv;
      int row = chunk * 16 + l4;
      gload_lds16(A + (size_t)(brow + row) * K + k0 + c8, sA + chunk * 512);
      gload_lds16(Bm + (size_t)(bcol + row) * K + k0 + c8, sB + chunk * 512);
    }
    __syncthreads();
    bf16x8 af[4], bfv[4];
    #pragma unroll
    for (int mi = 0; mi < 4; ++mi)
      af[mi] = *(const bf16x8*)(sA + (wr * 64 + mi * 16 + fr) * BK + fq * 8);
    #pragma unroll
    for (int ni = 0; ni < 4; ++ni)
      bfv[ni] = *(const bf16x8*)(sB + (wc * 64 + ni * 16 + fr) * BK + fq * 8);
    #pragma unroll
    for (int mi = 0; mi < 4; ++mi)
      #pragma unroll
      for (int ni = 0; ni < 4; ++ni)
        acc[mi][ni] = __builtin_amdgcn_mfma_f32_16x16x32_bf16(af[mi], bfv[ni], acc[mi][ni], 0, 0, 0);
    __syncthreads();
  }

  #pragma unroll
  for (int mi = 0; mi < 4; ++mi)
    #pragma unroll
    for (int ni = 0; ni < 4; ++ni) {
      int col = bcol + wc * 64 + ni * 16 + fr;
      #pragma unroll
      for (int j = 0; j < 4; ++j) {
        int row = brow + wr * 64 + mi * 16 + fq * 4 + j;
        out[(size_t)row * 4096 + col] = acc[mi][ni][j];
      }
    }
}

extern "C" void kernel_launch(void* const* d_in, const int* in_sizes, int n_in,
                              void* d_out, int out_size, void* d_ws, size_t ws_size,
                              hipStream_t stream) {
  const float* x    = (const float*)d_in[0];
  const float* cosT = (const float*)d_in[1];
  const float* sinT = (const float*)d_in[2];
  const float* qw   = (const float*)d_in[3];
  const float* qb   = (const float*)d_in[4];
  const float* kw   = (const float*)d_in[5];
  const float* kb   = (const float*)d_in[6];
  const float* vw   = (const float*)d_in[7];
  const float* vb   = (const float*)d_in[8];
  const float* ow   = (const float*)d_in[9];
  const int*   sp   = (const int*)d_in[10];
  float* out = (float*)d_out;
  char* ws = (char*)d_ws;

  // workspace layout (bytes); xb aliases Ob (disjoint lifetimes)
  bf16_t* xb  = (bf16_t*)(ws + 0);                       // 32MB  [b*s][4096]
  bf16_t* Ob  = (bf16_t*)(ws + 0);                       // 32MB  [b*s][4096]
  bf16_t* wT  = (bf16_t*)(ws + (size_t)33554432);        // 48MB  [6144][4096]
  bf16_t* owT = (bf16_t*)(ws + (size_t)83886080);        // 32MB  [4096][4096]
  bf16_t* Qr  = (bf16_t*)(ws + (size_t)117440512);       // 32MB  [2][32][2048][128]
  bf16_t* Kr  = (bf16_t*)(ws + (size_t)150994944);       // 8MB   [2][8][2048][128]
  bf16_t* Vr  = (bf16_t*)(ws + (size_t)159383552);       // 8MB   [2][8][2048][128]
  bf16_t* Vt  = (bf16_t*)(ws + (size_t)167772160);       // 8MB   [2][8][128][2048]

  k_cvt_bf16<<<16384, 256, 0, stream>>>(x, xb, 2 * 2048 * 4096 / 4);
  k_transpose_cvt<<<dim3(128, 128), 256, 0, stream>>>(qw, wT, 4096, 4096);
  k_transpose_cvt<<<dim3(32, 128), 256, 0, stream>>>(kw, wT + (size_t)4096 * 4096, 4096, 1024);
  k_transpose_cvt<<<dim3(32, 128), 256, 0, stream>>>(vw, wT + (size_t)5120 * 4096, 4096, 1024);
  k_transpose_cvt<<<dim3(128, 128), 256, 0, stream>>>(ow, owT, 4096, 4096);

  k_gemm_qkv<<<dim3(32, 48), 256, 0, stream>>>(xb, wT, qb, kb, vb, cosT, sinT, sp, Qr, Kr, Vr);
  k_transpose_bf16<<<dim3(4, 64, 16), 256, 0, stream>>>(Vr, Vt, 2048, 128);
  k_attn<<<dim3(32, 64), 256, 0, stream>>>(Qr, Kr, Vt, Ob);
  k_gemm_out<<<dim3(32, 32), 256, 0, stream>>>(Ob, owT, out);
}

// Round 2
// 1007.025 us; speedup vs baseline: 1.6339x; 1.6339x over previous
//
#include <hip/hip_runtime.h>
#include <hip/hip_bf16.h>
#include <stdint.h>

typedef __bf16 bf16_t;
typedef __bf16 bf16x8 __attribute__((ext_vector_type(8)));
typedef __bf16 bf16x4 __attribute__((ext_vector_type(4)));
typedef float f32x4 __attribute__((ext_vector_type(4)));

typedef __attribute__((address_space(1))) unsigned gu32;
typedef __attribute__((address_space(3))) unsigned lu32;

__device__ __forceinline__ unsigned short f2bf(float f) {
  unsigned u = __builtin_bit_cast(unsigned, f);
  unsigned r = (u + 0x7FFFu + ((u >> 16) & 1u)) >> 16;
  return (unsigned short)r;
}

__device__ __forceinline__ void gload_lds16(const bf16_t* g, bf16_t* l) {
  __builtin_amdgcn_global_load_lds((const gu32*)(const void*)g, (lu32*)(void*)l, 16, 0, 0);
}

// ---------------- fp32 -> bf16 convert (vectorized) ----------------
__global__ __launch_bounds__(256) void k_cvt_bf16(const float* __restrict__ in,
                                                  bf16_t* __restrict__ out, int n4) {
  int i = blockIdx.x * 256 + threadIdx.x;
  if (i >= n4) return;
  float4 v = ((const float4*)in)[i];
  ushort4 o;
  o.x = f2bf(v.x); o.y = f2bf(v.y); o.z = f2bf(v.z); o.w = f2bf(v.w);
  ((ushort4*)out)[i] = o;
}

// ---------------- fp32 RxC -> bf16 CxR transpose ----------------
__global__ __launch_bounds__(256) void k_transpose_cvt(const float* __restrict__ in,
                                                       bf16_t* __restrict__ out, int R, int C) {
  __shared__ float t[32][33];
  int c0 = blockIdx.x * 32, r0 = blockIdx.y * 32;
  int tx = threadIdx.x & 31, ty = threadIdx.x >> 5;
  #pragma unroll
  for (int r = 0; r < 4; ++r) {
    int rr = ty + r * 8;
    t[rr][tx] = in[(size_t)(r0 + rr) * C + c0 + tx];
  }
  __syncthreads();
  #pragma unroll
  for (int r = 0; r < 4; ++r) {
    int rr = ty + r * 8;
    ((unsigned short*)out)[(size_t)(c0 + rr) * R + r0 + tx] = f2bf(t[tx][rr]);
  }
}

// ---------------- bf16 batched RxC -> CxR transpose (for V) ----------------
__global__ __launch_bounds__(256) void k_transpose_bf16(const bf16_t* __restrict__ in,
                                                        bf16_t* __restrict__ out, int R, int C) {
  __shared__ unsigned short t[32][33];
  const unsigned short* ip = (const unsigned short*)in + (size_t)blockIdx.z * R * C;
  unsigned short* op = (unsigned short*)out + (size_t)blockIdx.z * R * C;
  int c0 = blockIdx.x * 32, r0 = blockIdx.y * 32;
  int tx = threadIdx.x & 31, ty = threadIdx.x >> 5;
  #pragma unroll
  for (int r = 0; r < 4; ++r) {
    int rr = ty + r * 8;
    t[rr][tx] = ip[(size_t)(r0 + rr) * C + c0 + tx];
  }
  __syncthreads();
  #pragma unroll
  for (int r = 0; r < 4; ++r) {
    int rr = ty + r * 8;
    op[(size_t)(c0 + rr) * R + r0 + tx] = t[tx][rr];
  }
}

// ---------------- QKV GEMM: xb[4096][4096] @ wT[6144][4096]^T ----------------
#define BK 32
__global__ __launch_bounds__(256) void k_gemm_qkv(
    const bf16_t* __restrict__ A, const bf16_t* __restrict__ Bm,
    const float* __restrict__ qb, const float* __restrict__ kb, const float* __restrict__ vb,
    const float* __restrict__ cosT, const float* __restrict__ sinT,
    const int* __restrict__ start_pos,
    bf16_t* __restrict__ Qr, bf16_t* __restrict__ Kr, bf16_t* __restrict__ Vr) {
  __shared__ __attribute__((aligned(16))) bf16_t sA[128 * BK];
  __shared__ __attribute__((aligned(16))) bf16_t sB[128 * BK];
  const int tid = threadIdx.x;
  const int lane = tid & 63;
  const int wv = tid >> 6;
  const int wr = wv >> 1, wc = wv & 1;
  const int brow = blockIdx.x * 128;
  const int bcol = blockIdx.y * 128;
  const int K = 4096;
  const int l4 = lane >> 2;
  const int c8 = (lane & 3) * 8;
  const int fr = lane & 15;
  const int fq = lane >> 4;

  f32x4 acc[4][4];
  #pragma unroll
  for (int i = 0; i < 4; ++i)
    #pragma unroll
    for (int j = 0; j < 4; ++j) acc[i][j] = (f32x4){0.f, 0.f, 0.f, 0.f};

  for (int k0 = 0; k0 < K; k0 += BK) {
    #pragma unroll
    for (int r = 0; r < 2; ++r) {
      int chunk = r * 4 + wv;
      int row = chunk * 16 + l4;
      gload_lds16(A + (size_t)(brow + row) * K + k0 + c8, sA + chunk * 512);
      gload_lds16(Bm + (size_t)(bcol + row) * K + k0 + c8, sB + chunk * 512);
    }
    __syncthreads();
    bf16x8 af[4], bfv[4];
    #pragma unroll
    for (int mi = 0; mi < 4; ++mi)
      af[mi] = *(const bf16x8*)(sA + (wr * 64 + mi * 16 + fr) * BK + fq * 8);
    #pragma unroll
    for (int ni = 0; ni < 4; ++ni)
      bfv[ni] = *(const bf16x8*)(sB + (wc * 64 + ni * 16 + fr) * BK + fq * 8);
    #pragma unroll
    for (int mi = 0; mi < 4; ++mi)
      #pragma unroll
      for (int ni = 0; ni < 4; ++ni)
        acc[mi][ni] = __builtin_amdgcn_mfma_f32_16x16x32_bf16(af[mi], bfv[ni], acc[mi][ni], 0, 0, 0);
    __syncthreads();
  }

  const int sp = *start_pos;
  #pragma unroll
  for (int mi = 0; mi < 4; ++mi) {
    #pragma unroll
    for (int ni = 0; ni < 4; ++ni) {
      int col = bcol + wc * 64 + ni * 16 + fr;
      float bias = (col < 4096) ? qb[col] : (col < 5120 ? kb[col - 4096] : vb[col - 5120]);
      #pragma unroll
      for (int j = 0; j < 4; ++j) {
        int row = brow + wr * 64 + mi * 16 + fq * 4 + j;
        int b = row >> 11, s = row & 2047;
        int d = col & 127;
        float v = acc[mi][ni][j] + bias;
        float partner = __shfl_xor(v, 1);
        if (col < 5120) {
          int dd = d >> 1;
          float cc = cosT[(size_t)(sp + s) * 64 + dd];
          float sn = sinT[(size_t)(sp + s) * 64 + dd];
          v = (d & 1) ? (partner * sn + v * cc) : (v * cc - partner * sn);
        }
        unsigned short bvv = f2bf(v);
        if (col < 4096) {
          int h = col >> 7;
          ((unsigned short*)Qr)[(((size_t)b * 32 + h) * 2048 + s) * 128 + d] = bvv;
        } else if (col < 5120) {
          int hk = (col - 4096) >> 7;
          ((unsigned short*)Kr)[(((size_t)b * 8 + hk) * 2048 + s) * 128 + d] = bvv;
        } else {
          int hk = (col - 5120) >> 7;
          ((unsigned short*)Vr)[(((size_t)b * 8 + hk) * 2048 + s) * 128 + d] = bvv;
        }
      }
    }
  }
}

// ---------------- flash attention: GQA, causal ----------------
// Block = 4 waves, 128 q-rows (32/wave). KV tiles of 32 staged in LDS
// (double-buffered, global_load_lds, XOR-swizzled), counted-vmcnt prefetch.
__global__ __launch_bounds__(256) void k_attn(
    const bf16_t* __restrict__ Qr, const bf16_t* __restrict__ Kr,
    const bf16_t* __restrict__ Vt, bf16_t* __restrict__ Ob) {
  // sK: [2 buf][32 rows][128 elems], row-swizzled byte^=((row&7)<<4)
  // sV: [2 buf][64 rows][128B]  row r = {d=2r | d=2r+1}, byte^=((r&7)<<4)
  __shared__ __attribute__((aligned(16))) bf16_t sK[2][4096];
  __shared__ __attribute__((aligned(16))) bf16_t sV[2][4096];
  __shared__ __attribute__((aligned(16))) bf16_t p_lds[4][2][16][40];

  const int tid = threadIdx.x;
  const int lane = tid & 63;
  const int w = tid >> 6;
  const int b = blockIdx.y >> 5, h = blockIdx.y & 31;
  const int hk = h >> 2;
  const int qt = (int)gridDim.x - 1 - (int)blockIdx.x;  // long blocks first
  const int q0b = qt * 128;
  const int T = qt * 4 + 4;
  const bf16_t* Qb = Qr + (((size_t)b * 32 + h) * 2048) * 128;
  const bf16_t* Kb = Kr + (((size_t)b * 8 + hk) * 2048) * 128;
  const bf16_t* Vb = Vt + (((size_t)b * 8 + hk) * 128) * 2048;
  const int fr = lane & 15, fq = lane >> 4;
  const int qw0 = q0b + w * 32;
  const float sc = 0.08838834764831845f;  // 1/sqrt(128)

  // ---- staging source offsets (constant across tiles) ----
  const int c0 = w * 64 + lane;        // chunk ids (16B each), i=0
  const int c1 = 256 + w * 64 + lane;  // i=1
  const int krow0 = c0 >> 4, krow1 = c1 >> 4;
  const int ko0 = ((c0 & 15) << 4) ^ ((krow0 & 7) << 4);
  const int ko1 = ((c1 & 15) << 4) ^ ((krow1 & 7) << 4);
  const size_t ksrc0 = (size_t)krow0 * 128 + (ko0 >> 1);
  const size_t ksrc1 = (size_t)krow1 * 128 + (ko1 >> 1);
  const int vr0 = c0 >> 3, vr1 = c1 >> 3;
  const int vo0 = ((c0 & 7) << 4) ^ ((vr0 & 7) << 4);
  const int vo1 = ((c1 & 7) << 4) ^ ((vr1 & 7) << 4);
  const size_t vsrc0 = (size_t)(2 * vr0 + (vo0 >> 6)) * 2048 + ((vo0 & 63) >> 1);
  const size_t vsrc1 = (size_t)(2 * vr1 + (vo1 >> 6)) * 2048 + ((vo1 & 63) >> 1);
  const int ldsA = (w * 64) * 8;          // lds elem offset, chunk group i=0
  const int ldsB = (256 + w * 64) * 8;    // i=1

  // ---- Q fragments (32 rows per wave) ----
  bf16x8 qf[2][4];
  #pragma unroll
  for (int f = 0; f < 2; ++f)
    #pragma unroll
    for (int c = 0; c < 4; ++c)
      qf[f][c] = *(const bf16x8*)(Qb + (size_t)(qw0 + f * 16 + fr) * 128 + c * 32 + fq * 8);

  f32x4 o[2][8];
  #pragma unroll
  for (int f = 0; f < 2; ++f)
    #pragma unroll
    for (int i = 0; i < 8; ++i) o[f][i] = (f32x4){0.f, 0.f, 0.f, 0.f};
  float m_s[2] = {-1e30f, -1e30f}, l_s[2] = {0.f, 0.f};

  const int kswz = (fr & 7) << 4;
  const int vlane = (fr >> 1) * 128 + ((((fr & 1) << 6) | (fq << 4)) ^ ((fr >> 1) << 4));

  auto STAGE = [&](int buf, int kv0) {
    const bf16_t* Kt = Kb + (size_t)kv0 * 128;
    const bf16_t* Vg = Vb + kv0;
    bf16_t* sk = &sK[buf][0];
    bf16_t* sv = &sV[buf][0];
    gload_lds16(Kt + ksrc0, sk + ldsA);
    gload_lds16(Kt + ksrc1, sk + ldsB);
    gload_lds16(Vg + vsrc0, sv + ldsA);
    gload_lds16(Vg + vsrc1, sv + ldsB);
  };

  STAGE(0, 0);
  int cur = 0;
  for (int t = 0; t < T; ++t) {
    const int kv0 = t * 32;
    if (t + 1 < T) {
      STAGE(cur ^ 1, kv0 + 32);
      asm volatile("s_waitcnt vmcnt(4)" ::: "memory");
    } else {
      asm volatile("s_waitcnt vmcnt(0)" ::: "memory");
    }
    __builtin_amdgcn_s_barrier();

    if (kv0 <= qw0 + 31) {
      const char* skc = (const char*)&sK[cur][0];
      const char* svc = (const char*)&sV[cur][0];
      // QK^T (swapped): st[f][sub] = S^T[kv=fq*4+j (+16*sub)][q=fr]
      f32x4 st[2][2];
      #pragma unroll
      for (int f = 0; f < 2; ++f)
        #pragma unroll
        for (int s2 = 0; s2 < 2; ++s2) st[f][s2] = (f32x4){0.f, 0.f, 0.f, 0.f};
      #pragma unroll
      for (int c = 0; c < 4; ++c) {
        const int off = (((c << 6) | (fq << 4)) ^ kswz);
        bf16x8 kf0 = *(const bf16x8*)(skc + fr * 256 + off);
        bf16x8 kf1 = *(const bf16x8*)(skc + 4096 + fr * 256 + off);
        st[0][0] = __builtin_amdgcn_mfma_f32_16x16x32_bf16(kf0, qf[0][c], st[0][0], 0, 0, 0);
        st[0][1] = __builtin_amdgcn_mfma_f32_16x16x32_bf16(kf1, qf[0][c], st[0][1], 0, 0, 0);
        st[1][0] = __builtin_amdgcn_mfma_f32_16x16x32_bf16(kf0, qf[1][c], st[1][0], 0, 0, 0);
        st[1][1] = __builtin_amdgcn_mfma_f32_16x16x32_bf16(kf1, qf[1][c], st[1][1], 0, 0, 0);
      }
      // softmax per q-fragment
      #pragma unroll
      for (int f = 0; f < 2; ++f) {
        const int qg = qw0 + f * 16 + fr;
        float p0[4], p1[4];
        float pm = -1e30f;
        #pragma unroll
        for (int j = 0; j < 4; ++j) {
          int kvr = kv0 + fq * 4 + j;
          float s0 = (kvr <= qg) ? st[f][0][j] * sc : -1e30f;
          float s1 = (kvr + 16 <= qg) ? st[f][1][j] * sc : -1e30f;
          p0[j] = s0; p1[j] = s1;
          pm = fmaxf(pm, fmaxf(s0, s1));
        }
        pm = fmaxf(pm, __shfl_xor(pm, 16));
        pm = fmaxf(pm, __shfl_xor(pm, 32));
        if (!__all(pm <= m_s[f] + 8.0f)) {  // T13 defer-max
          float m_new = fmaxf(m_s[f], pm);
          float scf = __expf(m_s[f] - m_new);
          l_s[f] *= scf;
          #pragma unroll
          for (int j = 0; j < 4; ++j) {
            float sj = __shfl(scf, fq * 4 + j);
            #pragma unroll
            for (int df = 0; df < 8; ++df) o[f][df][j] *= sj;
          }
          m_s[f] = m_new;
        }
        float ps = 0.f;
        #pragma unroll
        for (int j = 0; j < 4; ++j) {
          p0[j] = __expf(p0[j] - m_s[f]);
          p1[j] = __expf(p1[j] - m_s[f]);
          ps += p0[j] + p1[j];
        }
        ps += __shfl_xor(ps, 16);
        ps += __shfl_xor(ps, 32);
        l_s[f] += ps;
        bf16x4 pk0, pk1;
        #pragma unroll
        for (int j = 0; j < 4; ++j) { pk0[j] = (bf16_t)p0[j]; pk1[j] = (bf16_t)p1[j]; }
        *(bf16x4*)&p_lds[w][f][fr][fq * 4] = pk0;
        *(bf16x4*)&p_lds[w][f][fr][16 + fq * 4] = pk1;
      }
      asm volatile("s_waitcnt lgkmcnt(0)" ::: "memory");
      bf16x8 pa0 = *(const bf16x8*)&p_lds[w][0][fr][fq * 8];
      bf16x8 pa1 = *(const bf16x8*)&p_lds[w][1][fr][fq * 8];
      #pragma unroll
      for (int df = 0; df < 8; ++df) {
        bf16x8 vf = *(const bf16x8*)(svc + df * 1024 + vlane);
        o[0][df] = __builtin_amdgcn_mfma_f32_16x16x32_bf16(pa0, vf, o[0][df], 0, 0, 0);
        o[1][df] = __builtin_amdgcn_mfma_f32_16x16x32_bf16(pa1, vf, o[1][df], 0, 0, 0);
      }
    }
    __builtin_amdgcn_sched_barrier(0);
    __builtin_amdgcn_s_barrier();
    cur ^= 1;
  }

  // normalize + write O[b][s][h*128+d]
  #pragma unroll
  for (int f = 0; f < 2; ++f) {
    #pragma unroll
    for (int j = 0; j < 4; ++j) {
      float lj = __shfl(l_s[f], fq * 4 + j);
      float rl = 1.f / lj;
      int srow = qw0 + f * 16 + fq * 4 + j;
      #pragma unroll
      for (int df = 0; df < 8; ++df) {
        int dcol = df * 16 + fr;
        ((unsigned short*)Ob)[((size_t)b * 2048 + srow) * 4096 + h * 128 + dcol] =
            f2bf(o[f][df][j] * rl);
      }
    }
  }
}

// ---------------- out projection GEMM: Ob @ owT^T -> f32 out ----------------
__global__ __launch_bounds__(256) void k_gemm_out(
    const bf16_t* __restrict__ A, const bf16_t* __restrict__ Bm, float* __restrict__ out) {
  __shared__ __attribute__((aligned(16))) bf16_t sA[128 * BK];
  __shared__ __attribute__((aligned(16))) bf16_t sB[128 * BK];
  const int tid = threadIdx.x;
  const int lane = tid & 63;
  const int wv = tid >> 6;
  const int wr = wv >> 1, wc = wv & 1;
  const int brow = blockIdx.x * 128;
  const int bcol = blockIdx.y * 128;
  const int K = 4096;
  const int l4 = lane >> 2;
  const int c8 = (lane & 3) * 8;
  const int fr = lane & 15;
  const int fq = lane >> 4;

  f32x4 acc[4][4];
  #pragma unroll
  for (int i = 0; i < 4; ++i)
    #pragma unroll
    for (int j = 0; j < 4; ++j) acc[i][j] = (f32x4){0.f, 0.f, 0.f, 0.f};

  for (int k0 = 0; k0 < K; k0 += BK) {
    #pragma unroll
    for (int r = 0; r < 2; ++r) {
      int chunk = r * 4 + wv;
      int row = chunk * 16 + l4;
      gload_lds16(A + (size_t)(brow + row) * K + k0 + c8, sA + chunk * 512);
      gload_lds16(Bm + (size_t)(bcol + row) * K + k0 + c8, sB + chunk * 512);
    }
    __syncthreads();
    bf16x8 af[4], bfv[4];
    #pragma unroll
    for (int mi = 0; mi < 4; ++mi)
      af[mi] = *(const bf16x8*)(sA + (wr * 64 + mi * 16 + fr) * BK + fq * 8);
    #pragma unroll
    for (int ni = 0; ni < 4; ++ni)
      bfv[ni] = *(const bf16x8*)(sB + (wc * 64 + ni * 16 + fr) * BK + fq * 8);
    #pragma unroll
    for (int mi = 0; mi < 4; ++mi)
      #pragma unroll
      for (int ni = 0; ni < 4; ++ni)
        acc[mi][ni] = __builtin_amdgcn_mfma_f32_16x16x32_bf16(af[mi], bfv[ni], acc[mi][ni], 0, 0, 0);
    __syncthreads();
  }

  #pragma unroll
  for (int mi = 0; mi < 4; ++mi)
    #pragma unroll
    for (int ni = 0; ni < 4; ++ni) {
      int col = bcol + wc * 64 + ni * 16 + fr;
      #pragma unroll
      for (int j = 0; j < 4; ++j) {
        int row = brow + wr * 64 + mi * 16 + fq * 4 + j;
        out[(size_t)row * 4096 + col] = acc[mi][ni][j];
      }
    }
}

extern "C" void kernel_launch(void* const* d_in, const int* in_sizes, int n_in,
                              void* d_out, int out_size, void* d_ws, size_t ws_size,
                              hipStream_t stream) {
  const float* x    = (const float*)d_in[0];
  const float* cosT = (const float*)d_in[1];
  const float* sinT = (const float*)d_in[2];
  const float* qw   = (const float*)d_in[3];
  const float* qb   = (const float*)d_in[4];
  const float* kw   = (const float*)d_in[5];
  const float* kb   = (const float*)d_in[6];
  const float* vw   = (const float*)d_in[7];
  const float* vb   = (const float*)d_in[8];
  const float* ow   = (const float*)d_in[9];
  const int*   sp   = (const int*)d_in[10];
  float* out = (float*)d_out;
  char* ws = (char*)d_ws;

  bf16_t* xb  = (bf16_t*)(ws + 0);                       // 32MB  [b*s][4096]
  bf16_t* Ob  = (bf16_t*)(ws + 0);                       // 32MB  [b*s][4096]
  bf16_t* wT  = (bf16_t*)(ws + (size_t)33554432);        // 48MB  [6144][4096]
  bf16_t* owT = (bf16_t*)(ws + (size_t)83886080);        // 32MB  [4096][4096]
  bf16_t* Qr  = (bf16_t*)(ws + (size_t)117440512);       // 32MB  [2][32][2048][128]
  bf16_t* Kr  = (bf16_t*)(ws + (size_t)150994944);       // 8MB   [2][8][2048][128]
  bf16_t* Vr  = (bf16_t*)(ws + (size_t)159383552);       // 8MB   [2][8][2048][128]
  bf16_t* Vt  = (bf16_t*)(ws + (size_t)167772160);       // 8MB   [2][8][128][2048]

  k_cvt_bf16<<<16384, 256, 0, stream>>>(x, xb, 2 * 2048 * 4096 / 4);
  k_transpose_cvt<<<dim3(128, 128), 256, 0, stream>>>(qw, wT, 4096, 4096);
  k_transpose_cvt<<<dim3(32, 128), 256, 0, stream>>>(kw, wT + (size_t)4096 * 4096, 4096, 1024);
  k_transpose_cvt<<<dim3(32, 128), 256, 0, stream>>>(vw, wT + (size_t)5120 * 4096, 4096, 1024);
  k_transpose_cvt<<<dim3(128, 128), 256, 0, stream>>>(ow, owT, 4096, 4096);

  k_gemm_qkv<<<dim3(32, 48), 256, 0, stream>>>(xb, wT, qb, kb, vb, cosT, sinT, sp, Qr, Kr, Vr);
  k_transpose_bf16<<<dim3(4, 64, 16), 256, 0, stream>>>(Vr, Vt, 2048, 128);
  k_attn<<<dim3(16, 64), 256, 0, stream>>>(Qr, Kr, Vt, Ob);
  k_gemm_out<<<dim3(32, 32), 256, 0, stream>>>(Ob, owT, out);
}

// Round 3
// 958.691 us; speedup vs baseline: 1.7162x; 1.0504x over previous
//
#include <hip/hip_runtime.h>
#include <hip/hip_bf16.h>
#include <stdint.h>

typedef __bf16 bf16_t;
typedef __bf16 bf16x8 __attribute__((ext_vector_type(8)));
typedef __bf16 bf16x4 __attribute__((ext_vector_type(4)));
typedef float f32x4 __attribute__((ext_vector_type(4)));

typedef __attribute__((address_space(1))) unsigned gu32;
typedef __attribute__((address_space(3))) unsigned lu32;

__device__ __forceinline__ unsigned short f2bf(float f) {
  unsigned u = __builtin_bit_cast(unsigned, f);
  unsigned r = (u + 0x7FFFu + ((u >> 16) & 1u)) >> 16;
  return (unsigned short)r;
}

__device__ __forceinline__ void gload_lds16(const bf16_t* g, bf16_t* l) {
  __builtin_amdgcn_global_load_lds((const gu32*)(const void*)g, (lu32*)(void*)l, 16, 0, 0);
}

// ---------------- fp32 -> bf16 convert (vectorized) ----------------
__global__ __launch_bounds__(256) void k_cvt_bf16(const float* __restrict__ in,
                                                  bf16_t* __restrict__ out, int n4) {
  int i = blockIdx.x * 256 + threadIdx.x;
  if (i >= n4) return;
  float4 v = ((const float4*)in)[i];
  ushort4 o;
  o.x = f2bf(v.x); o.y = f2bf(v.y); o.z = f2bf(v.z); o.w = f2bf(v.w);
  ((ushort4*)out)[i] = o;
}

// ---------------- fp32 RxC -> bf16 CxR transpose ----------------
__global__ __launch_bounds__(256) void k_transpose_cvt(const float* __restrict__ in,
                                                       bf16_t* __restrict__ out, int R, int C) {
  __shared__ float t[32][33];
  int c0 = blockIdx.x * 32, r0 = blockIdx.y * 32;
  int tx = threadIdx.x & 31, ty = threadIdx.x >> 5;
  #pragma unroll
  for (int r = 0; r < 4; ++r) {
    int rr = ty + r * 8;
    t[rr][tx] = in[(size_t)(r0 + rr) * C + c0 + tx];
  }
  __syncthreads();
  #pragma unroll
  for (int r = 0; r < 4; ++r) {
    int rr = ty + r * 8;
    ((unsigned short*)out)[(size_t)(c0 + rr) * R + r0 + tx] = f2bf(t[tx][rr]);
  }
}

// ---------------- bf16 batched RxC -> CxR transpose (for V) ----------------
__global__ __launch_bounds__(256) void k_transpose_bf16(const bf16_t* __restrict__ in,
                                                        bf16_t* __restrict__ out, int R, int C) {
  __shared__ unsigned short t[32][33];
  const unsigned short* ip = (const unsigned short*)in + (size_t)blockIdx.z * R * C;
  unsigned short* op = (unsigned short*)out + (size_t)blockIdx.z * R * C;
  int c0 = blockIdx.x * 32, r0 = blockIdx.y * 32;
  int tx = threadIdx.x & 31, ty = threadIdx.x >> 5;
  #pragma unroll
  for (int r = 0; r < 4; ++r) {
    int rr = ty + r * 8;
    t[rr][tx] = ip[(size_t)(r0 + rr) * C + c0 + tx];
  }
  __syncthreads();
  #pragma unroll
  for (int r = 0; r < 4; ++r) {
    int rr = ty + r * 8;
    op[(size_t)(c0 + rr) * R + r0 + tx] = t[tx][rr];
  }
}

// ---------------- QKV GEMM: xb[4096][4096] @ wT[6144][4096]^T ----------------
#define BK 32
__global__ __launch_bounds__(256) void k_gemm_qkv(
    const bf16_t* __restrict__ A, const bf16_t* __restrict__ Bm,
    const float* __restrict__ qb, const float* __restrict__ kb, const float* __restrict__ vb,
    const float* __restrict__ cosT, const float* __restrict__ sinT,
    const int* __restrict__ start_pos,
    bf16_t* __restrict__ Qr, bf16_t* __restrict__ Kr, bf16_t* __restrict__ Vr) {
  __shared__ __attribute__((aligned(16))) bf16_t sA[128 * BK];
  __shared__ __attribute__((aligned(16))) bf16_t sB[128 * BK];
  __shared__ __attribute__((aligned(16))) bf16_t sET[128][132];  // [d][s] transposed tile
  const int tid = threadIdx.x;
  const int lane = tid & 63;
  const int wv = tid >> 6;
  const int wr = wv >> 1, wc = wv & 1;
  // T1 XCD-aware bijective swizzle (nwg=1536, 1536%8==0)
  const int bid = blockIdx.y * gridDim.x + blockIdx.x;
  const int swz = (bid & 7) * 192 + (bid >> 3);
  const int brow = (swz & 31) * 128;
  const int bcol = (swz >> 5) * 128;
  const int K = 4096;
  const int l4 = lane >> 2;
  const int c8 = (lane & 3) * 8;
  const int fr = lane & 15;
  const int fq = lane >> 4;

  f32x4 acc[4][4];
  #pragma unroll
  for (int i = 0; i < 4; ++i)
    #pragma unroll
    for (int j = 0; j < 4; ++j) acc[i][j] = (f32x4){0.f, 0.f, 0.f, 0.f};

  for (int k0 = 0; k0 < K; k0 += BK) {
    #pragma unroll
    for (int r = 0; r < 2; ++r) {
      int chunk = r * 4 + wv;
      int row = chunk * 16 + l4;
      gload_lds16(A + (size_t)(brow + row) * K + k0 + c8, sA + chunk * 512);
      gload_lds16(Bm + (size_t)(bcol + row) * K + k0 + c8, sB + chunk * 512);
    }
    __syncthreads();
    bf16x8 af[4], bfv[4];
    #pragma unroll
    for (int mi = 0; mi < 4; ++mi)
      af[mi] = *(const bf16x8*)(sA + (wr * 64 + mi * 16 + fr) * BK + fq * 8);
    #pragma unroll
    for (int ni = 0; ni < 4; ++ni)
      bfv[ni] = *(const bf16x8*)(sB + (wc * 64 + ni * 16 + fr) * BK + fq * 8);
    #pragma unroll
    for (int mi = 0; mi < 4; ++mi)
      #pragma unroll
      for (int ni = 0; ni < 4; ++ni)
        acc[mi][ni] = __builtin_amdgcn_mfma_f32_16x16x32_bf16(af[mi], bfv[ni], acc[mi][ni], 0, 0, 0);
    __syncthreads();
  }

  // ---- epilogue: bias + RoPE in regs, LDS-transpose, coalesced 16B stores ----
  const int sp = *start_pos;
  const bool isQ = bcol < 4096;
  const bool isV = bcol >= 5120;
  const int s0 = brow & 2047;
  #pragma unroll
  for (int mi = 0; mi < 4; ++mi) {
    #pragma unroll
    for (int ni = 0; ni < 4; ++ni) {
      int lc = wc * 64 + ni * 16 + fr;  // local col = d
      float bias = isQ ? qb[bcol + lc] : (!isV ? kb[bcol - 4096 + lc] : vb[bcol - 5120 + lc]);
      int lrb = wr * 64 + mi * 16 + fq * 4;  // local row base
      bf16x4 pk;
      #pragma unroll
      for (int j = 0; j < 4; ++j) {
        float v = acc[mi][ni][j] + bias;
        float partner = __shfl_xor(v, 1);
        if (!isV) {
          int dd = lc >> 1;
          int s = s0 + lrb + j;
          float cc = cosT[(size_t)(sp + s) * 64 + dd];
          float sn = sinT[(size_t)(sp + s) * 64 + dd];
          v = (lc & 1) ? (partner * sn + v * cc) : (v * cc - partner * sn);
        }
        pk[j] = (bf16_t)v;
      }
      *(bf16x4*)&sET[lc][lrb] = pk;
    }
  }
  __syncthreads();
  const int b = brow >> 11;
  unsigned short* dst;
  if (isQ)
    dst = (unsigned short*)Qr + (((size_t)b * 32 + (bcol >> 7)) * 2048 + s0) * 128;
  else if (!isV)
    dst = (unsigned short*)Kr + (((size_t)b * 8 + ((bcol - 4096) >> 7)) * 2048 + s0) * 128;
  else
    dst = (unsigned short*)Vr + (((size_t)b * 8 + ((bcol - 5120) >> 7)) * 2048 + s0) * 128;
  #pragma unroll
  for (int i = 0; i < 8; ++i) {
    int chunk = i * 256 + tid;   // 0..2047
    int sl = chunk >> 4;         // s row 0..127
    int dp = (chunk & 15) * 8;   // d start
    unsigned short tmp[8];
    #pragma unroll
    for (int k = 0; k < 8; ++k) tmp[k] = ((unsigned short*)sET)[(dp + k) * 132 + sl];
    uint4 ov;
    ov.x = (unsigned)tmp[0] | ((unsigned)tmp[1] << 16);
    ov.y = (unsigned)tmp[2] | ((unsigned)tmp[3] << 16);
    ov.z = (unsigned)tmp[4] | ((unsigned)tmp[5] << 16);
    ov.w = (unsigned)tmp[6] | ((unsigned)tmp[7] << 16);
    *(uint4*)(dst + (size_t)sl * 128 + dp) = ov;
  }
}

// ---------------- flash attention: GQA, causal ----------------
__global__ __launch_bounds__(256) void k_attn(
    const bf16_t* __restrict__ Qr, const bf16_t* __restrict__ Kr,
    const bf16_t* __restrict__ Vt, bf16_t* __restrict__ Ob) {
  __shared__ __attribute__((aligned(16))) bf16_t sK[2][4096];
  __shared__ __attribute__((aligned(16))) bf16_t sV[2][4096];
  __shared__ __attribute__((aligned(16))) bf16_t p_lds[4][16][40];

  const int tid = threadIdx.x;
  const int lane = tid & 63;
  const int w = tid >> 6;
  const int b = blockIdx.y >> 5, h = blockIdx.y & 31;
  const int hk = h >> 2;
  const int qt = (int)gridDim.x - 1 - (int)blockIdx.x;  // long blocks first
  const int q0b = qt * 128;
  const int T = qt * 4 + 4;
  const bf16_t* Qb = Qr + (((size_t)b * 32 + h) * 2048) * 128;
  const bf16_t* Kb = Kr + (((size_t)b * 8 + hk) * 2048) * 128;
  const bf16_t* Vb = Vt + (((size_t)b * 8 + hk) * 128) * 2048;
  const int fr = lane & 15, fq = lane >> 4;
  const int qw0 = q0b + w * 32;
  const float sc = 0.08838834764831845f;  // 1/sqrt(128)

  const int c0 = w * 64 + lane;
  const int c1 = 256 + w * 64 + lane;
  const int krow0 = c0 >> 4, krow1 = c1 >> 4;
  const int ko0 = ((c0 & 15) << 4) ^ ((krow0 & 7) << 4);
  const int ko1 = ((c1 & 15) << 4) ^ ((krow1 & 7) << 4);
  const size_t ksrc0 = (size_t)krow0 * 128 + (ko0 >> 1);
  const size_t ksrc1 = (size_t)krow1 * 128 + (ko1 >> 1);
  const int vr0 = c0 >> 3, vr1 = c1 >> 3;
  const int vo0 = ((c0 & 7) << 4) ^ ((vr0 & 7) << 4);
  const int vo1 = ((c1 & 7) << 4) ^ ((vr1 & 7) << 4);
  const size_t vsrc0 = (size_t)(2 * vr0 + (vo0 >> 6)) * 2048 + ((vo0 & 63) >> 1);
  const size_t vsrc1 = (size_t)(2 * vr1 + (vo1 >> 6)) * 2048 + ((vo1 & 63) >> 1);
  const int ldsA = (w * 64) * 8;
  const int ldsB = (256 + w * 64) * 8;

  bf16x8 qf[2][4];
  #pragma unroll
  for (int f = 0; f < 2; ++f)
    #pragma unroll
    for (int c = 0; c < 4; ++c)
      qf[f][c] = *(const bf16x8*)(Qb + (size_t)(qw0 + f * 16 + fr) * 128 + c * 32 + fq * 8);

  f32x4 o[2][8];
  #pragma unroll
  for (int f = 0; f < 2; ++f)
    #pragma unroll
    for (int i = 0; i < 8; ++i) o[f][i] = (f32x4){0.f, 0.f, 0.f, 0.f};
  float m_s[2] = {-1e30f, -1e30f}, l_s[2] = {0.f, 0.f};

  const int kswz = (fr & 7) << 4;
  const int vlane = (fr >> 1) * 128 + ((((fr & 1) << 6) | (fq << 4)) ^ ((fr >> 1) << 4));

  auto STAGE = [&](int buf, int kv0) {
    const bf16_t* Kt = Kb + (size_t)kv0 * 128;
    const bf16_t* Vg = Vb + kv0;
    bf16_t* sk = &sK[buf][0];
    bf16_t* sv = &sV[buf][0];
    gload_lds16(Kt + ksrc0, sk + ldsA);
    gload_lds16(Kt + ksrc1, sk + ldsB);
    gload_lds16(Vg + vsrc0, sv + ldsA);
    gload_lds16(Vg + vsrc1, sv + ldsB);
  };

  STAGE(0, 0);
  int cur = 0;
  for (int t = 0; t < T; ++t) {
    const int kv0 = t * 32;
    if (t + 1 < T) {
      STAGE(cur ^ 1, kv0 + 32);
      asm volatile("s_waitcnt vmcnt(4)" ::: "memory");
    } else {
      asm volatile("s_waitcnt vmcnt(0)" ::: "memory");
    }
    __builtin_amdgcn_s_barrier();

    if (kv0 <= qw0 + 31) {
      const char* skc = (const char*)&sK[cur][0];
      const char* svc = (const char*)&sV[cur][0];
      f32x4 st[2][2];
      #pragma unroll
      for (int f = 0; f < 2; ++f)
        #pragma unroll
        for (int s2 = 0; s2 < 2; ++s2) st[f][s2] = (f32x4){0.f, 0.f, 0.f, 0.f};
      __builtin_amdgcn_s_setprio(1);
      #pragma unroll
      for (int c = 0; c < 4; ++c) {
        const int off = (((c << 6) | (fq << 4)) ^ kswz);
        bf16x8 kf0 = *(const bf16x8*)(skc + fr * 256 + off);
        bf16x8 kf1 = *(const bf16x8*)(skc + 4096 + fr * 256 + off);
        st[0][0] = __builtin_amdgcn_mfma_f32_16x16x32_bf16(kf0, qf[0][c], st[0][0], 0, 0, 0);
        st[0][1] = __builtin_amdgcn_mfma_f32_16x16x32_bf16(kf1, qf[0][c], st[0][1], 0, 0, 0);
        st[1][0] = __builtin_amdgcn_mfma_f32_16x16x32_bf16(kf0, qf[1][c], st[1][0], 0, 0, 0);
        st[1][1] = __builtin_amdgcn_mfma_f32_16x16x32_bf16(kf1, qf[1][c], st[1][1], 0, 0, 0);
      }
      __builtin_amdgcn_s_setprio(0);
      bf16x8 pa[2];
      #pragma unroll
      for (int f = 0; f < 2; ++f) {
        const int qg = qw0 + f * 16 + fr;
        float p0[4], p1[4];
        float pm = -1e30f;
        #pragma unroll
        for (int j = 0; j < 4; ++j) {
          int kvr = kv0 + fq * 4 + j;
          float s0v = (kvr <= qg) ? st[f][0][j] * sc : -1e30f;
          float s1v = (kvr + 16 <= qg) ? st[f][1][j] * sc : -1e30f;
          p0[j] = s0v; p1[j] = s1v;
          pm = fmaxf(pm, fmaxf(s0v, s1v));
        }
        pm = fmaxf(pm, __shfl_xor(pm, 16));
        pm = fmaxf(pm, __shfl_xor(pm, 32));
        if (!__all(pm <= m_s[f] + 8.0f)) {  // T13 defer-max
          float m_new = fmaxf(m_s[f], pm);
          float scf = __expf(m_s[f] - m_new);
          l_s[f] *= scf;
          #pragma unroll
          for (int j = 0; j < 4; ++j) {
            float sj = __shfl(scf, fq * 4 + j);
            #pragma unroll
            for (int df = 0; df < 8; ++df) o[f][df][j] *= sj;
          }
          m_s[f] = m_new;
        }
        float ps = 0.f;
        #pragma unroll
        for (int j = 0; j < 4; ++j) {
          p0[j] = __expf(p0[j] - m_s[f]);
          p1[j] = __expf(p1[j] - m_s[f]);
          ps += p0[j] + p1[j];
        }
        ps += __shfl_xor(ps, 16);
        ps += __shfl_xor(ps, 32);
        l_s[f] += ps;
        bf16x4 pk0, pk1;
        #pragma unroll
        for (int j = 0; j < 4; ++j) { pk0[j] = (bf16_t)p0[j]; pk1[j] = (bf16_t)p1[j]; }
        *(bf16x4*)&p_lds[w][fr][fq * 4] = pk0;
        *(bf16x4*)&p_lds[w][fr][16 + fq * 4] = pk1;
        asm volatile("s_waitcnt lgkmcnt(0)" ::: "memory");
        pa[f] = *(const bf16x8*)&p_lds[w][fr][fq * 8];
        asm volatile("s_waitcnt lgkmcnt(0)" ::: "memory");  // read done before next f's stores
      }
      __builtin_amdgcn_s_setprio(1);
      #pragma unroll
      for (int df = 0; df < 8; ++df) {
        bf16x8 vf = *(const bf16x8*)(svc + df * 1024 + vlane);
        o[0][df] = __builtin_amdgcn_mfma_f32_16x16x32_bf16(pa[0], vf, o[0][df], 0, 0, 0);
        o[1][df] = __builtin_amdgcn_mfma_f32_16x16x32_bf16(pa[1], vf, o[1][df], 0, 0, 0);
      }
      __builtin_amdgcn_s_setprio(0);
    }
    __builtin_amdgcn_sched_barrier(0);
    __builtin_amdgcn_s_barrier();
    cur ^= 1;
  }

  #pragma unroll
  for (int f = 0; f < 2; ++f) {
    #pragma unroll
    for (int j = 0; j < 4; ++j) {
      float lj = __shfl(l_s[f], fq * 4 + j);
      float rl = 1.f / lj;
      int srow = qw0 + f * 16 + fq * 4 + j;
      #pragma unroll
      for (int df = 0; df < 8; ++df) {
        int dcol = df * 16 + fr;
        ((unsigned short*)Ob)[((size_t)b * 2048 + srow) * 4096 + h * 128 + dcol] =
            f2bf(o[f][df][j] * rl);
      }
    }
  }
}

// ---------------- out projection GEMM: Ob @ owT^T -> f32 out ----------------
__global__ __launch_bounds__(256) void k_gemm_out(
    const bf16_t* __restrict__ A, const bf16_t* __restrict__ Bm, float* __restrict__ out) {
  __shared__ __attribute__((aligned(16))) bf16_t sA[128 * BK];
  __shared__ __attribute__((aligned(16))) bf16_t sB[128 * BK];
  const int tid = threadIdx.x;
  const int lane = tid & 63;
  const int wv = tid >> 6;
  const int wr = wv >> 1, wc = wv & 1;
  const int bid = blockIdx.y * gridDim.x + blockIdx.x;
  const int swz = (bid & 7) * 128 + (bid >> 3);
  const int brow = (swz & 31) * 128;
  const int bcol = (swz >> 5) * 128;
  const int K = 4096;
  const int l4 = lane >> 2;
  const int c8 = (lane & 3) * 8;
  const int fr = lane & 15;
  const int fq = lane >> 4;

  f32x4 acc[4][4];
  #pragma unroll
  for (int i = 0; i < 4; ++i)
    #pragma unroll
    for (int j = 0; j < 4; ++j) acc[i][j] = (f32x4){0.f, 0.f, 0.f, 0.f};

  for (int k0 = 0; k0 < K; k0 += BK) {
    #pragma unroll
    for (int r = 0; r < 2; ++r) {
      int chunk = r * 4 + wv;
      int row = chunk * 16 + l4;
      gload_lds16(A + (size_t)(brow + row) * K + k0 + c8, sA + chunk * 512);
      gload_lds16(Bm + (size_t)(bcol + row) * K + k0 + c8, sB + chunk * 512);
    }
    __syncthreads();
    bf16x8 af[4], bfv[4];
    #pragma unroll
    for (int mi = 0; mi < 4; ++mi)
      af[mi] = *(const bf16x8*)(sA + (wr * 64 + mi * 16 + fr) * BK + fq * 8);
    #pragma unroll
    for (int ni = 0; ni < 4; ++ni)
      bfv[ni] = *(const bf16x8*)(sB + (wc * 64 + ni * 16 + fr) * BK + fq * 8);
    #pragma unroll
    for (int mi = 0; mi < 4; ++mi)
      #pragma unroll
      for (int ni = 0; ni < 4; ++ni)
        acc[mi][ni] = __builtin_amdgcn_mfma_f32_16x16x32_bf16(af[mi], bfv[ni], acc[mi][ni], 0, 0, 0);
    __syncthreads();
  }

  #pragma unroll
  for (int mi = 0; mi < 4; ++mi)
    #pragma unroll
    for (int ni = 0; ni < 4; ++ni) {
      int col = bcol + wc * 64 + ni * 16 + fr;
      #pragma unroll
      for (int j = 0; j < 4; ++j) {
        int row = brow + wr * 64 + mi * 16 + fq * 4 + j;
        out[(size_t)row * 4096 + col] = acc[mi][ni][j];
      }
    }
}

extern "C" void kernel_launch(void* const* d_in, const int* in_sizes, int n_in,
                              void* d_out, int out_size, void* d_ws, size_t ws_size,
                              hipStream_t stream) {
  const float* x    = (const float*)d_in[0];
  const float* cosT = (const float*)d_in[1];
  const float* sinT = (const float*)d_in[2];
  const float* qw   = (const float*)d_in[3];
  const float* qb   = (const float*)d_in[4];
  const float* kw   = (const float*)d_in[5];
  const float* kb   = (const float*)d_in[6];
  const float* vw   = (const float*)d_in[7];
  const float* vb   = (const float*)d_in[8];
  const float* ow   = (const float*)d_in[9];
  const int*   sp   = (const int*)d_in[10];
  float* out = (float*)d_out;
  char* ws = (char*)d_ws;

  bf16_t* xb  = (bf16_t*)(ws + 0);                       // 32MB  [b*s][4096]
  bf16_t* Ob  = (bf16_t*)(ws + 0);                       // 32MB  [b*s][4096]
  bf16_t* wT  = (bf16_t*)(ws + (size_t)33554432);        // 48MB  [6144][4096]
  bf16_t* owT = (bf16_t*)(ws + (size_t)83886080);        // 32MB  [4096][4096]
  bf16_t* Qr  = (bf16_t*)(ws + (size_t)117440512);       // 32MB  [2][32][2048][128]
  bf16_t* Kr  = (bf16_t*)(ws + (size_t)150994944);       // 8MB   [2][8][2048][128]
  bf16_t* Vr  = (bf16_t*)(ws + (size_t)159383552);       // 8MB   [2][8][2048][128]
  bf16_t* Vt  = (bf16_t*)(ws + (size_t)167772160);       // 8MB   [2][8][128][2048]

  k_cvt_bf16<<<16384, 256, 0, stream>>>(x, xb, 2 * 2048 * 4096 / 4);
  k_transpose_cvt<<<dim3(128, 128), 256, 0, stream>>>(qw, wT, 4096, 4096);
  k_transpose_cvt<<<dim3(32, 128), 256, 0, stream>>>(kw, wT + (size_t)4096 * 4096, 4096, 1024);
  k_transpose_cvt<<<dim3(32, 128), 256, 0, stream>>>(vw, wT + (size_t)5120 * 4096, 4096, 1024);
  k_transpose_cvt<<<dim3(128, 128), 256, 0, stream>>>(ow, owT, 4096, 4096);

  k_gemm_qkv<<<dim3(32, 48), 256, 0, stream>>>(xb, wT, qb, kb, vb, cosT, sinT, sp, Qr, Kr, Vr);
  k_transpose_bf16<<<dim3(4, 64, 16), 256, 0, stream>>>(Vr, Vt, 2048, 128);
  k_attn<<<dim3(16, 64), 256, 0, stream>>>(Qr, Kr, Vt, Ob);
  k_gemm_out<<<dim3(32, 32), 256, 0, stream>>>(Ob, owT, out);
}

// Round 4
// 920.543 us; speedup vs baseline: 1.7874x; 1.0414x over previous
//
#include <hip/hip_runtime.h>
#include <hip/hip_bf16.h>
#include <stdint.h>

typedef __bf16 bf16_t;
typedef __bf16 bf16x8 __attribute__((ext_vector_type(8)));
typedef __bf16 bf16x4 __attribute__((ext_vector_type(4)));
typedef float f32x4 __attribute__((ext_vector_type(4)));

typedef __attribute__((address_space(1))) unsigned gu32;
typedef __attribute__((address_space(3))) unsigned lu32;

__device__ __forceinline__ unsigned short f2bf(float f) {
  unsigned u = __builtin_bit_cast(unsigned, f);
  unsigned r = (u + 0x7FFFu + ((u >> 16) & 1u)) >> 16;
  return (unsigned short)r;
}

__device__ __forceinline__ void gload_lds16(const bf16_t* g, bf16_t* l) {
  __builtin_amdgcn_global_load_lds((const gu32*)(const void*)g, (lu32*)(void*)l, 16, 0, 0);
}

#define BARRIER() do { asm volatile("" ::: "memory"); __builtin_amdgcn_s_barrier(); asm volatile("" ::: "memory"); } while (0)
#define WAITV(N) asm volatile("s_waitcnt vmcnt(" #N ")" ::: "memory")

// ---------------- fp32 -> bf16 convert (vectorized) ----------------
__global__ __launch_bounds__(256) void k_cvt_bf16(const float* __restrict__ in,
                                                  bf16_t* __restrict__ out, int n4) {
  int i = blockIdx.x * 256 + threadIdx.x;
  if (i >= n4) return;
  float4 v = ((const float4*)in)[i];
  ushort4 o;
  o.x = f2bf(v.x); o.y = f2bf(v.y); o.z = f2bf(v.z); o.w = f2bf(v.w);
  ((ushort4*)out)[i] = o;
}

// ---------------- fp32 RxC -> bf16 CxR transpose ----------------
__global__ __launch_bounds__(256) void k_transpose_cvt(const float* __restrict__ in,
                                                       bf16_t* __restrict__ out, int R, int C) {
  __shared__ float t[32][33];
  int c0 = blockIdx.x * 32, r0 = blockIdx.y * 32;
  int tx = threadIdx.x & 31, ty = threadIdx.x >> 5;
  #pragma unroll
  for (int r = 0; r < 4; ++r) {
    int rr = ty + r * 8;
    t[rr][tx] = in[(size_t)(r0 + rr) * C + c0 + tx];
  }
  __syncthreads();
  #pragma unroll
  for (int r = 0; r < 4; ++r) {
    int rr = ty + r * 8;
    ((unsigned short*)out)[(size_t)(c0 + rr) * R + r0 + tx] = f2bf(t[tx][rr]);
  }
}

// ---------------- bf16 batched RxC -> CxR transpose (for V) ----------------
__global__ __launch_bounds__(256) void k_transpose_bf16(const bf16_t* __restrict__ in,
                                                        bf16_t* __restrict__ out, int R, int C) {
  __shared__ unsigned short t[32][33];
  const unsigned short* ip = (const unsigned short*)in + (size_t)blockIdx.z * R * C;
  unsigned short* op = (unsigned short*)out + (size_t)blockIdx.z * R * C;
  int c0 = blockIdx.x * 32, r0 = blockIdx.y * 32;
  int tx = threadIdx.x & 31, ty = threadIdx.x >> 5;
  #pragma unroll
  for (int r = 0; r < 4; ++r) {
    int rr = ty + r * 8;
    t[rr][tx] = ip[(size_t)(r0 + rr) * C + c0 + tx];
  }
  __syncthreads();
  #pragma unroll
  for (int r = 0; r < 4; ++r) {
    int rr = ty + r * 8;
    op[(size_t)(c0 + rr) * R + r0 + tx] = t[tx][rr];
  }
}

// ================= 256x256 8-wave counted-vmcnt GEMM =================
// A[M][4096], Bm[N][4096] (both K-major rows). BK=64 split into 2 k-half
// planes of [256][32]; LDS ring = 4 plane-pairs (2 buf x 2 kh), 128KB.
// Per K-tile: 4 phases (kh x mh), 16 MFMA each, stage 2 gload_lds/phase,
// vmcnt(4) at pair ends (never 0 in steady state).
// MODE 0: QKV epilogue (bias+RoPE+per-head scatter). MODE 1: fp32 C.
template <int MODE>
__global__ __launch_bounds__(512, 2) void k_gemm256(
    const bf16_t* __restrict__ A, const bf16_t* __restrict__ Bm,
    const float* __restrict__ qb, const float* __restrict__ kb, const float* __restrict__ vb,
    const float* __restrict__ cosT, const float* __restrict__ sinT,
    const int* __restrict__ start_pos,
    bf16_t* __restrict__ Qr, bf16_t* __restrict__ Kr, bf16_t* __restrict__ Vr,
    float* __restrict__ outF, int nbq) {
  extern __shared__ char smem[];
  bf16_t* sAe = (bf16_t*)smem;                 // [2][2][256][32]
  bf16_t* sBe = (bf16_t*)(smem + 65536);       // [2][2][256][32]
  const int tid = threadIdx.x;
  const int lane = tid & 63;
  const int w = tid >> 6;
  const int wr = w >> 2, wc = w & 3;
  const int fr = lane & 15, fq = lane >> 4;
  // XCD-aware bijective swizzle (grid % 8 == 0)
  const int g = (blockIdx.x & 7) * nbq + (blockIdx.x >> 3);
  const int brow = (g & 15) * 256;
  const int bcol = (g >> 4) * 256;

  // staging source (pre-inverse-swizzled): instr covers 16 rows x 4 slots
  const int srow = w * 16 + (lane >> 2);
  const int scol = (((lane & 3) ^ ((lane >> 3) & 3))) * 8;
  const bf16_t* Ag = A + (size_t)(brow + srow) * 4096 + scol;
  const bf16_t* Bg = Bm + (size_t)(bcol + srow) * 4096 + scol;
  bf16_t* sAw = sAe + w * 512;
  bf16_t* sBw = sBe + w * 512;

  // LDS read offsets (elements), swizzled slot = fq ^ ((row>>1)&3)
  const int swz = (fr >> 1) & 3;
  const int aoff = (wr * 128 + fr) * 32 + (fq ^ swz) * 8;
  const int boff = (wc * 64 + fr) * 32 + (fq ^ swz) * 8;

  f32x4 acc[8][4];
  #pragma unroll
  for (int m = 0; m < 8; ++m)
    #pragma unroll
    for (int n = 0; n < 4; ++n) acc[m][n] = (f32x4){0.f, 0.f, 0.f, 0.f};

  auto stageA = [&](int buf, int kh, int kt) {
    const bf16_t* gp = Ag + (size_t)kt * 64 + kh * 32;
    bf16_t* lp = sAw + (buf * 2 + kh) * 8192;
    gload_lds16(gp, lp);
    gload_lds16(gp + (size_t)128 * 4096, lp + 4096);
  };
  auto stageB = [&](int buf, int kh, int kt) {
    const bf16_t* gp = Bg + (size_t)kt * 64 + kh * 32;
    bf16_t* lp = sBw + (buf * 2 + kh) * 8192;
    gload_lds16(gp, lp);
    gload_lds16(gp + (size_t)128 * 4096, lp + 4096);
  };

  bf16x8 afv[4], bfv[4];
#define LOADB(BUF, KH) { const bf16_t* p = sBe + ((BUF) * 2 + (KH)) * 8192 + boff; \
  _Pragma("unroll") for (int n = 0; n < 4; ++n) bfv[n] = *(const bf16x8*)(p + n * 512); }
#define LOADA(BUF, KH, MH) { const bf16_t* p = sAe + ((BUF) * 2 + (KH)) * 8192 + aoff + (MH) * 2048; \
  _Pragma("unroll") for (int m = 0; m < 4; ++m) afv[m] = *(const bf16x8*)(p + m * 512); }
#define MFMAH(MH) do { __builtin_amdgcn_s_setprio(1); \
  _Pragma("unroll") for (int m = 0; m < 4; ++m) \
    _Pragma("unroll") for (int n = 0; n < 4; ++n) \
      acc[(MH) * 4 + m][n] = __builtin_amdgcn_mfma_f32_16x16x32_bf16(afv[m], bfv[n], acc[(MH) * 4 + m][n], 0, 0, 0); \
  __builtin_amdgcn_s_setprio(0); } while (0)

  // prologue: pairs 0 (t0,k0) and 1 (t0,k1); wait pair 0 (4 newer in flight)
  stageA(0, 0, 0); stageB(0, 0, 0);
  stageA(0, 1, 0); stageB(0, 1, 0);
  WAITV(4);
  BARRIER();

  for (int kt = 0; kt < 63; ++kt) {
    const int cur = kt & 1, nxt = cur ^ 1;
    // pair (kt, k0)
    LOADB(cur, 0); LOADA(cur, 0, 0); stageA(nxt, 0, kt + 1);
    BARRIER(); MFMAH(0); BARRIER();
    LOADA(cur, 0, 1); stageB(nxt, 0, kt + 1);
    BARRIER(); MFMAH(1); WAITV(4); BARRIER();
    // pair (kt, k1)
    LOADB(cur, 1); LOADA(cur, 1, 0); stageA(nxt, 1, kt + 1);
    BARRIER(); MFMAH(0); BARRIER();
    LOADA(cur, 1, 1); stageB(nxt, 1, kt + 1);
    BARRIER(); MFMAH(1); WAITV(4); BARRIER();
  }
  // tail kt = 63 (cur = 1), no staging
  LOADB(1, 0); LOADA(1, 0, 0); BARRIER(); MFMAH(0); BARRIER();
  LOADA(1, 0, 1); BARRIER(); MFMAH(1); WAITV(0); BARRIER();
  LOADB(1, 1); LOADA(1, 1, 0); BARRIER(); MFMAH(0); BARRIER();
  LOADA(1, 1, 1); MFMAH(1);
#undef LOADB
#undef LOADA
#undef MFMAH

  __syncthreads();

  if constexpr (MODE == 0) {
    // bias + RoPE + per-head transposed scatter (two 128-col passes)
    const int sp2 = *start_pos;
    const int b = brow >> 11;
    const int s0 = brow & 2047;
    const bool isV = (bcol >= 5120);
    unsigned short* sET = (unsigned short*)smem;  // [128][268]
    const int hh = wc >> 1;
    const int dbase = (wc & 1) * 64;
    #pragma unroll
    for (int pass = 0; pass < 2; ++pass) {
      if (hh == pass) {
        #pragma unroll
        for (int n = 0; n < 4; ++n) {
          const int d = dbase + n * 16 + fr;      // 0..127
          const int col = bcol + pass * 128 + d;  // global col
          float bias;
          if (bcol < 4096) bias = qb[col];
          else if (bcol < 5120) bias = kb[col - 4096];
          else bias = vb[col - 5120];
          #pragma unroll
          for (int m = 0; m < 8; ++m) {
            const int sl = wr * 128 + m * 16 + fq * 4;
            bf16x4 pk;
            #pragma unroll
            for (int j = 0; j < 4; ++j) {
              float v = acc[m][n][j] + bias;
              float partner = __shfl_xor(v, 1);
              if (!isV) {
                int s = s0 + sl + j;
                float cc = cosT[(size_t)(sp2 + s) * 64 + (d >> 1)];
                float sn = sinT[(size_t)(sp2 + s) * 64 + (d >> 1)];
                v = (d & 1) ? (partner * sn + v * cc) : (v * cc - partner * sn);
              }
              pk[j] = (bf16_t)v;
            }
            *(bf16x4*)&sET[d * 268 + sl] = pk;
          }
        }
      }
      __syncthreads();
      const int cb = bcol + pass * 128;
      unsigned short* Hdst;
      if (cb < 4096)      Hdst = (unsigned short*)Qr + (((size_t)b * 32 + (cb >> 7)) * 2048 + s0) * 128;
      else if (cb < 5120) Hdst = (unsigned short*)Kr + (((size_t)b * 8 + ((cb - 4096) >> 7)) * 2048 + s0) * 128;
      else                Hdst = (unsigned short*)Vr + (((size_t)b * 8 + ((cb - 5120) >> 7)) * 2048 + s0) * 128;
      #pragma unroll
      for (int i = 0; i < 8; ++i) {
        int c = i * 512 + tid;  // 0..4095 chunks of 16B
        int sl = c >> 4;
        int dp = (c & 15) * 8;
        unsigned short tmp[8];
        #pragma unroll
        for (int k2 = 0; k2 < 8; ++k2) tmp[k2] = sET[(dp + k2) * 268 + sl];
        uint4 ov;
        ov.x = (unsigned)tmp[0] | ((unsigned)tmp[1] << 16);
        ov.y = (unsigned)tmp[2] | ((unsigned)tmp[3] << 16);
        ov.z = (unsigned)tmp[4] | ((unsigned)tmp[5] << 16);
        ov.w = (unsigned)tmp[6] | ((unsigned)tmp[7] << 16);
        *(uint4*)(Hdst + (size_t)sl * 128 + dp) = ov;
      }
      __syncthreads();
    }
  } else {
    #pragma unroll
    for (int m = 0; m < 8; ++m)
      #pragma unroll
      for (int n = 0; n < 4; ++n) {
        const int col = bcol + wc * 64 + n * 16 + fr;
        #pragma unroll
        for (int j = 0; j < 4; ++j) {
          const int row = brow + wr * 128 + m * 16 + fq * 4 + j;
          outF[(size_t)row * 4096 + col] = acc[m][n][j];
        }
      }
  }
}

// ---------------- flash attention: GQA, causal (unchanged) ----------------
__global__ __launch_bounds__(256) void k_attn(
    const bf16_t* __restrict__ Qr, const bf16_t* __restrict__ Kr,
    const bf16_t* __restrict__ Vt, bf16_t* __restrict__ Ob) {
  __shared__ __attribute__((aligned(16))) bf16_t sK[2][4096];
  __shared__ __attribute__((aligned(16))) bf16_t sV[2][4096];
  __shared__ __attribute__((aligned(16))) bf16_t p_lds[4][16][40];

  const int tid = threadIdx.x;
  const int lane = tid & 63;
  const int w = tid >> 6;
  const int b = blockIdx.y >> 5, h = blockIdx.y & 31;
  const int hk = h >> 2;
  const int qt = (int)gridDim.x - 1 - (int)blockIdx.x;
  const int q0b = qt * 128;
  const int T = qt * 4 + 4;
  const bf16_t* Qb = Qr + (((size_t)b * 32 + h) * 2048) * 128;
  const bf16_t* Kb = Kr + (((size_t)b * 8 + hk) * 2048) * 128;
  const bf16_t* Vb = Vt + (((size_t)b * 8 + hk) * 128) * 2048;
  const int fr = lane & 15, fq = lane >> 4;
  const int qw0 = q0b + w * 32;
  const float sc = 0.08838834764831845f;

  const int c0 = w * 64 + lane;
  const int c1 = 256 + w * 64 + lane;
  const int krow0 = c0 >> 4, krow1 = c1 >> 4;
  const int ko0 = ((c0 & 15) << 4) ^ ((krow0 & 7) << 4);
  const int ko1 = ((c1 & 15) << 4) ^ ((krow1 & 7) << 4);
  const size_t ksrc0 = (size_t)krow0 * 128 + (ko0 >> 1);
  const size_t ksrc1 = (size_t)krow1 * 128 + (ko1 >> 1);
  const int vr0 = c0 >> 3, vr1 = c1 >> 3;
  const int vo0 = ((c0 & 7) << 4) ^ ((vr0 & 7) << 4);
  const int vo1 = ((c1 & 7) << 4) ^ ((vr1 & 7) << 4);
  const size_t vsrc0 = (size_t)(2 * vr0 + (vo0 >> 6)) * 2048 + ((vo0 & 63) >> 1);
  const size_t vsrc1 = (size_t)(2 * vr1 + (vo1 >> 6)) * 2048 + ((vo1 & 63) >> 1);
  const int ldsA = (w * 64) * 8;
  const int ldsB = (256 + w * 64) * 8;

  bf16x8 qf[2][4];
  #pragma unroll
  for (int f = 0; f < 2; ++f)
    #pragma unroll
    for (int c = 0; c < 4; ++c)
      qf[f][c] = *(const bf16x8*)(Qb + (size_t)(qw0 + f * 16 + fr) * 128 + c * 32 + fq * 8);

  f32x4 o[2][8];
  #pragma unroll
  for (int f = 0; f < 2; ++f)
    #pragma unroll
    for (int i = 0; i < 8; ++i) o[f][i] = (f32x4){0.f, 0.f, 0.f, 0.f};
  float m_s[2] = {-1e30f, -1e30f}, l_s[2] = {0.f, 0.f};

  const int kswz = (fr & 7) << 4;
  const int vlane = (fr >> 1) * 128 + ((((fr & 1) << 6) | (fq << 4)) ^ ((fr >> 1) << 4));

  auto STAGE = [&](int buf, int kv0) {
    const bf16_t* Kt = Kb + (size_t)kv0 * 128;
    const bf16_t* Vg = Vb + kv0;
    bf16_t* sk = &sK[buf][0];
    bf16_t* sv = &sV[buf][0];
    gload_lds16(Kt + ksrc0, sk + ldsA);
    gload_lds16(Kt + ksrc1, sk + ldsB);
    gload_lds16(Vg + vsrc0, sv + ldsA);
    gload_lds16(Vg + vsrc1, sv + ldsB);
  };

  STAGE(0, 0);
  int cur = 0;
  for (int t = 0; t < T; ++t) {
    const int kv0 = t * 32;
    if (t + 1 < T) {
      STAGE(cur ^ 1, kv0 + 32);
      asm volatile("s_waitcnt vmcnt(4)" ::: "memory");
    } else {
      asm volatile("s_waitcnt vmcnt(0)" ::: "memory");
    }
    __builtin_amdgcn_s_barrier();

    if (kv0 <= qw0 + 31) {
      const char* skc = (const char*)&sK[cur][0];
      const char* svc = (const char*)&sV[cur][0];
      f32x4 st[2][2];
      #pragma unroll
      for (int f = 0; f < 2; ++f)
        #pragma unroll
        for (int s2 = 0; s2 < 2; ++s2) st[f][s2] = (f32x4){0.f, 0.f, 0.f, 0.f};
      __builtin_amdgcn_s_setprio(1);
      #pragma unroll
      for (int c = 0; c < 4; ++c) {
        const int off = (((c << 6) | (fq << 4)) ^ kswz);
        bf16x8 kf0 = *(const bf16x8*)(skc + fr * 256 + off);
        bf16x8 kf1 = *(const bf16x8*)(skc + 4096 + fr * 256 + off);
        st[0][0] = __builtin_amdgcn_mfma_f32_16x16x32_bf16(kf0, qf[0][c], st[0][0], 0, 0, 0);
        st[0][1] = __builtin_amdgcn_mfma_f32_16x16x32_bf16(kf1, qf[0][c], st[0][1], 0, 0, 0);
        st[1][0] = __builtin_amdgcn_mfma_f32_16x16x32_bf16(kf0, qf[1][c], st[1][0], 0, 0, 0);
        st[1][1] = __builtin_amdgcn_mfma_f32_16x16x32_bf16(kf1, qf[1][c], st[1][1], 0, 0, 0);
      }
      __builtin_amdgcn_s_setprio(0);
      bf16x8 pa[2];
      #pragma unroll
      for (int f = 0; f < 2; ++f) {
        const int qg = qw0 + f * 16 + fr;
        float p0[4], p1[4];
        float pm = -1e30f;
        #pragma unroll
        for (int j = 0; j < 4; ++j) {
          int kvr = kv0 + fq * 4 + j;
          float s0v = (kvr <= qg) ? st[f][0][j] * sc : -1e30f;
          float s1v = (kvr + 16 <= qg) ? st[f][1][j] * sc : -1e30f;
          p0[j] = s0v; p1[j] = s1v;
          pm = fmaxf(pm, fmaxf(s0v, s1v));
        }
        pm = fmaxf(pm, __shfl_xor(pm, 16));
        pm = fmaxf(pm, __shfl_xor(pm, 32));
        if (!__all(pm <= m_s[f] + 8.0f)) {
          float m_new = fmaxf(m_s[f], pm);
          float scf = __expf(m_s[f] - m_new);
          l_s[f] *= scf;
          #pragma unroll
          for (int j = 0; j < 4; ++j) {
            float sj = __shfl(scf, fq * 4 + j);
            #pragma unroll
            for (int df = 0; df < 8; ++df) o[f][df][j] *= sj;
          }
          m_s[f] = m_new;
        }
        float ps = 0.f;
        #pragma unroll
        for (int j = 0; j < 4; ++j) {
          p0[j] = __expf(p0[j] - m_s[f]);
          p1[j] = __expf(p1[j] - m_s[f]);
          ps += p0[j] + p1[j];
        }
        ps += __shfl_xor(ps, 16);
        ps += __shfl_xor(ps, 32);
        l_s[f] += ps;
        bf16x4 pk0, pk1;
        #pragma unroll
        for (int j = 0; j < 4; ++j) { pk0[j] = (bf16_t)p0[j]; pk1[j] = (bf16_t)p1[j]; }
        *(bf16x4*)&p_lds[w][fr][fq * 4] = pk0;
        *(bf16x4*)&p_lds[w][fr][16 + fq * 4] = pk1;
        asm volatile("s_waitcnt lgkmcnt(0)" ::: "memory");
        pa[f] = *(const bf16x8*)&p_lds[w][fr][fq * 8];
        asm volatile("s_waitcnt lgkmcnt(0)" ::: "memory");
      }
      __builtin_amdgcn_s_setprio(1);
      #pragma unroll
      for (int df = 0; df < 8; ++df) {
        bf16x8 vf = *(const bf16x8*)(svc + df * 1024 + vlane);
        o[0][df] = __builtin_amdgcn_mfma_f32_16x16x32_bf16(pa[0], vf, o[0][df], 0, 0, 0);
        o[1][df] = __builtin_amdgcn_mfma_f32_16x16x32_bf16(pa[1], vf, o[1][df], 0, 0, 0);
      }
      __builtin_amdgcn_s_setprio(0);
    }
    __builtin_amdgcn_sched_barrier(0);
    __builtin_amdgcn_s_barrier();
    cur ^= 1;
  }

  #pragma unroll
  for (int f = 0; f < 2; ++f) {
    #pragma unroll
    for (int j = 0; j < 4; ++j) {
      float lj = __shfl(l_s[f], fq * 4 + j);
      float rl = 1.f / lj;
      int srow = qw0 + f * 16 + fq * 4 + j;
      #pragma unroll
      for (int df = 0; df < 8; ++df) {
        int dcol = df * 16 + fr;
        ((unsigned short*)Ob)[((size_t)b * 2048 + srow) * 4096 + h * 128 + dcol] =
            f2bf(o[f][df][j] * rl);
      }
    }
  }
}

extern "C" void kernel_launch(void* const* d_in, const int* in_sizes, int n_in,
                              void* d_out, int out_size, void* d_ws, size_t ws_size,
                              hipStream_t stream) {
  const float* x    = (const float*)d_in[0];
  const float* cosT = (const float*)d_in[1];
  const float* sinT = (const float*)d_in[2];
  const float* qw   = (const float*)d_in[3];
  const float* qb   = (const float*)d_in[4];
  const float* kw   = (const float*)d_in[5];
  const float* kb   = (const float*)d_in[6];
  const float* vw   = (const float*)d_in[7];
  const float* vb   = (const float*)d_in[8];
  const float* ow   = (const float*)d_in[9];
  const int*   sp   = (const int*)d_in[10];
  float* out = (float*)d_out;
  char* ws = (char*)d_ws;

  bf16_t* xb  = (bf16_t*)(ws + 0);                       // 32MB  [b*s][4096]
  bf16_t* Ob  = (bf16_t*)(ws + 0);                       // 32MB  [b*s][4096]
  bf16_t* wT  = (bf16_t*)(ws + (size_t)33554432);        // 48MB  [6144][4096]
  bf16_t* owT = (bf16_t*)(ws + (size_t)83886080);        // 32MB  [4096][4096]
  bf16_t* Qr  = (bf16_t*)(ws + (size_t)117440512);       // 32MB  [2][32][2048][128]
  bf16_t* Kr  = (bf16_t*)(ws + (size_t)150994944);       // 8MB   [2][8][2048][128]
  bf16_t* Vr  = (bf16_t*)(ws + (size_t)159383552);       // 8MB   [2][8][2048][128]
  bf16_t* Vt  = (bf16_t*)(ws + (size_t)167772160);       // 8MB   [2][8][128][2048]

  const int shmem = 131072;
  hipFuncSetAttribute((const void*)&k_gemm256<0>, hipFuncAttributeMaxDynamicSharedMemorySize, shmem);
  hipFuncSetAttribute((const void*)&k_gemm256<1>, hipFuncAttributeMaxDynamicSharedMemorySize, shmem);

  k_cvt_bf16<<<16384, 256, 0, stream>>>(x, xb, 2 * 2048 * 4096 / 4);
  k_transpose_cvt<<<dim3(128, 128), 256, 0, stream>>>(qw, wT, 4096, 4096);
  k_transpose_cvt<<<dim3(32, 128), 256, 0, stream>>>(kw, wT + (size_t)4096 * 4096, 4096, 1024);
  k_transpose_cvt<<<dim3(32, 128), 256, 0, stream>>>(vw, wT + (size_t)5120 * 4096, 4096, 1024);
  k_transpose_cvt<<<dim3(128, 128), 256, 0, stream>>>(ow, owT, 4096, 4096);

  k_gemm256<0><<<384, 512, shmem, stream>>>(xb, wT, qb, kb, vb, cosT, sinT, sp, Qr, Kr, Vr, nullptr, 48);
  k_transpose_bf16<<<dim3(4, 64, 16), 256, 0, stream>>>(Vr, Vt, 2048, 128);
  k_attn<<<dim3(16, 64), 256, 0, stream>>>(Qr, Kr, Vt, Ob);
  k_gemm256<1><<<256, 512, shmem, stream>>>(Ob, owT, nullptr, nullptr, nullptr, nullptr, nullptr, nullptr,
                                            nullptr, nullptr, nullptr, out, 32);
}